// Round 14
// baseline (187.542 us; speedup 1.0000x reference)
//
#include <hip/hip_runtime.h>
#include <hip/hip_fp16.h>

// ---------------------------------------------------------------------------
// ClassificationKNNLoss on MI355X — R14: mega-kernel at 16 waves/CU.
//   k_prep : norms + bf16 convert with granule-XOR swizzle (+ zeroes d_out)
//   k_mega : ONE 1024-thr block per CU owns 32 rows x ALL 8192 cols. B read
//            DIRECT from global (L2-hot; no write stream). Zero main-loop
//            barriers/LDS. Per-thread sorted top-2 keys + denom in regs;
//            top-16 + label + loss merged in-block.
// R13 lesson: structure is right (aux path 28us->2us, FETCH 16.8MB, conflicts
// 0) but 512 thr = 2 waves/SIMD couldn't hide L2 latency (occ 19%, VALU 31%).
// R14 doubles resident waves: 1024 thr, wave w sweeps tiles w+16i.
// ---------------------------------------------------------------------------

typedef __attribute__((ext_vector_type(8))) short s8v;       // 8 x bf16 (4 VGPR)
typedef __attribute__((ext_vector_type(4))) float f32x4;     // MFMA acc

#define NK 256

template <bool B> struct BoolC { static constexpr bool value = B; };

// ws byte offsets
#define OFF_NRM 0                // f32[8192]
#define OFF_XB  32768            // u16[8192*256] swizzled bf16 (4.19MB)

__device__ __forceinline__ unsigned short f2bf(float f) {
  unsigned u = __float_as_uint(f);
  return (unsigned short)((u + 0x7FFFu + ((u >> 16) & 1u)) >> 16);  // RNE
}

__device__ __forceinline__ unsigned umin32(unsigned a, unsigned b) { return a < b ? a : b; }
__device__ __forceinline__ unsigned umax32(unsigned a, unsigned b) { return a > b ? a : b; }

// ---------------------------------------------------------------- k_prep ----
// xb[(r,k)] stored at u16 index r*256 + ((k>>3) ^ (r&7))*8 + (k&7)
__global__ __launch_bounds__(256) void k_prep(const float* __restrict__ x,
                                              unsigned short* __restrict__ xb,
                                              float* __restrict__ nrm,
                                              float* __restrict__ out) {
  if (blockIdx.x == 0 && threadIdx.x == 0) out[0] = 0.0f;
  const int w = threadIdx.x >> 6, l = threadIdx.x & 63;
  const int r = blockIdx.x * 4 + w;
  const float4 xv = *reinterpret_cast<const float4*>(x + r * NK + l * 4);
  float ns = xv.x * xv.x + xv.y * xv.y + xv.z * xv.z + xv.w * xv.w;
  ns += __shfl_xor(ns, 1);  ns += __shfl_xor(ns, 2);  ns += __shfl_xor(ns, 4);
  ns += __shfl_xor(ns, 8);  ns += __shfl_xor(ns, 16); ns += __shfl_xor(ns, 32);
  if (l == 0) nrm[r] = ns;
  ushort4 bv;
  bv.x = f2bf(xv.x); bv.y = f2bf(xv.y); bv.z = f2bf(xv.z); bv.w = f2bf(xv.w);
  const int gs = (l >> 1) ^ (r & 7);
  *reinterpret_cast<ushort4*>(xb + r * NK + gs * 8 + (l & 1) * 4) = bv;
}

// ---------------------------------------------------------------- k_mega ----
// 256 blocks (1/CU) x 1024 thr (16 waves). Block = rows [rb*32, rb*32+32).
// Wave w sweeps 64-col tiles t = w + 16i (i=0..7).
__global__ __launch_bounds__(1024, 4) void k_mega(const unsigned short* __restrict__ xb,
                                                  const float* __restrict__ nrm,
                                                  const int* __restrict__ y,
                                                  float* __restrict__ out) {
  __shared__ float ncsAll[8192];      // all column norms (32KB)
  __shared__ float dpart[32];         // per-row denom
  __shared__ unsigned cl[32][512];    // per-row candidate lists (64KB)
  const int tid = threadIdx.x;
  const int w = tid >> 6, l = tid & 63, l15 = l & 15, l4 = l >> 4;
  const int rb = blockIdx.x;
  const int rowbase = rb * 32;

  #pragma unroll
  for (int j = 0; j < 8; ++j) ncsAll[tid + j * 1024] = nrm[tid + j * 1024];
  if (tid < 32) dpart[tid] = 0.0f;

  s8v A[2][8];  // the block's 32 rows x K=256, register-resident (per wave)
  #pragma unroll
  for (int rf = 0; rf < 2; ++rf) {
    const int rr = rowbase + rf * 16 + l15;
    #pragma unroll
    for (int kf = 0; kf < 8; ++kf) {
      const int g = ((kf << 2) | l4) ^ (rr & 7);
      A[rf][kf] = *reinterpret_cast<const s8v*>(xb + rr * NK + g * 8);
    }
  }
  float nr[2][4], dn[2][4];
  unsigned s0[2][4], s1[2][4];  // per-thread sorted top-2 keys per row
  #pragma unroll
  for (int rf = 0; rf < 2; ++rf)
    #pragma unroll
    for (int q = 0; q < 4; ++q) {
      nr[rf][q] = nrm[rowbase + rf * 16 + l4 * 4 + q];
      dn[rf][q] = 0.0f;
      s0[rf][q] = 0xFFFFFFFFu;
      s1[rf][q] = 0xFFFFFFFFu;
    }

  int koff[8];  // per-lane granule byte offset within a column's 512B row
  #pragma unroll
  for (int kf = 0; kf < 8; ++kf)
    koff[kf] = ((((kf << 2) | l4) ^ (l15 & 7)) << 4);
  const char* xbc = (const char*)xb;
  const int tdg = rb >> 1;            // tile containing this block's diagonal

  __syncthreads();                    // ncsAll/dpart published

  for (int i = 0; i < 8; ++i) {
    const int t = w + i * 16;
    const int cbase = t * 64;
    const char* bp = xbc + (size_t)(cbase + l15) * 512;
    f32x4 acc[2][4];
    #pragma unroll
    for (int cf = 0; cf < 4; ++cf) {
      f32x4 z = {0.f, 0.f, 0.f, 0.f};
      acc[0][cf] = z; acc[1][cf] = z;
    }
    #pragma unroll
    for (int kf = 0; kf < 8; ++kf) {
      const s8v b0 = *reinterpret_cast<const s8v*>(bp + koff[kf]);
      const s8v b1 = *reinterpret_cast<const s8v*>(bp + 8192 + koff[kf]);
      const s8v b2 = *reinterpret_cast<const s8v*>(bp + 16384 + koff[kf]);
      const s8v b3 = *reinterpret_cast<const s8v*>(bp + 24576 + koff[kf]);
      acc[0][0] = __builtin_amdgcn_mfma_f32_16x16x32_bf16(A[0][kf], b0, acc[0][0], 0, 0, 0);
      acc[1][0] = __builtin_amdgcn_mfma_f32_16x16x32_bf16(A[1][kf], b0, acc[1][0], 0, 0, 0);
      acc[0][1] = __builtin_amdgcn_mfma_f32_16x16x32_bf16(A[0][kf], b1, acc[0][1], 0, 0, 0);
      acc[1][1] = __builtin_amdgcn_mfma_f32_16x16x32_bf16(A[1][kf], b1, acc[1][1], 0, 0, 0);
      acc[0][2] = __builtin_amdgcn_mfma_f32_16x16x32_bf16(A[0][kf], b2, acc[0][2], 0, 0, 0);
      acc[1][2] = __builtin_amdgcn_mfma_f32_16x16x32_bf16(A[1][kf], b2, acc[1][2], 0, 0, 0);
      acc[0][3] = __builtin_amdgcn_mfma_f32_16x16x32_bf16(A[0][kf], b3, acc[0][3], 0, 0, 0);
      acc[1][3] = __builtin_amdgcn_mfma_f32_16x16x32_bf16(A[1][kf], b3, acc[1][3], 0, 0, 0);
    }
    float nc[4];
    #pragma unroll
    for (int cf = 0; cf < 4; ++cf) nc[cf] = ncsAll[cbase + cf * 16 + l15];
    auto epi = [&](auto dgc) {
      constexpr bool DG = decltype(dgc)::value;
      #pragma unroll
      for (int rf = 0; rf < 2; ++rf)
        #pragma unroll
        for (int cf = 0; cf < 4; ++cf) {
          const unsigned colg = (unsigned)(cbase + cf * 16 + l15);
          #pragma unroll
          for (int q = 0; q < 4; ++q) {
            const unsigned rowg = (unsigned)(rowbase + rf * 16 + l4 * 4 + q);
            float sq = fmaf(acc[rf][cf][q], -2.0f, nr[rf][q] + nc[cf]);
            if (DG) sq = fmaxf(sq, 0.0f);
            const float d = __builtin_amdgcn_sqrtf(sq);
            float e = __expf(-d);
            unsigned k = ((unsigned)__half_as_ushort(__float2half(d)) << 16) | colg;
            if (DG) {
              const bool nd = (rowg != colg);
              e = nd ? e : 0.0f;
              k = nd ? k : 0xFFFFFFFFu;
            }
            dn[rf][q] += e;
            const unsigned ev = umax32(s0[rf][q], k);
            s0[rf][q] = umin32(s0[rf][q], k);
            s1[rf][q] = umin32(s1[rf][q], ev);
          }
        }
    };
    if (t == tdg) epi(BoolC<true>{});
    else          epi(BoolC<false>{});
  }

  // ---- in-block merge (replaces k_fin) ----
  #pragma unroll
  for (int rf = 0; rf < 2; ++rf)
    #pragma unroll
    for (int q = 0; q < 4; ++q) {
      float vs = dn[rf][q];
      vs += __shfl_xor(vs, 1); vs += __shfl_xor(vs, 2);
      vs += __shfl_xor(vs, 4); vs += __shfl_xor(vs, 8);
      const int row32 = rf * 16 + l4 * 4 + q;
      if (l15 == 0) atomicAdd(&dpart[row32], vs);
      cl[row32][w * 32 + l15 * 2]     = s0[rf][q];
      cl[row32][w * 32 + l15 * 2 + 1] = s1[rf][q];
    }
  __syncthreads();

  float wsum = 0.0f;
  for (int rr = 0; rr < 2; ++rr) {   // wave w finalizes rows 2w, 2w+1
    const int row = w * 2 + rr;
    unsigned kk[8];
    #pragma unroll
    for (int j = 0; j < 8; ++j) kk[j] = cl[row][l * 8 + j];
    unsigned myKey = 0xFFFFFFFFu;
    for (int pp = 0; pp < 16; ++pp) {
      unsigned lm = kk[0];
      #pragma unroll
      for (int j = 1; j < 8; ++j) lm = umin32(lm, kk[j]);
      unsigned m = lm;
      m = umin32(m, __shfl_xor(m, 1));  m = umin32(m, __shfl_xor(m, 2));
      m = umin32(m, __shfl_xor(m, 4));  m = umin32(m, __shfl_xor(m, 8));
      m = umin32(m, __shfl_xor(m, 16)); m = umin32(m, __shfl_xor(m, 32));
      const unsigned long long bal = __ballot(lm == m);
      const int owner = (int)__ffsll(bal) - 1;
      if (l == owner) {
        bool f = false;
        #pragma unroll
        for (int j = 0; j < 8; ++j)
          if (!f && kk[j] == m) { kk[j] = 0xFFFFFFFFu; f = true; }
      }
      if (l == pp) myKey = m;
    }
    const float logden = __logf(dpart[row]);
    float contrib = 0.0f, cmf = 0.0f;
    if (l < 16 && myKey != 0xFFFFFFFFu) {
      const int col = (int)(myKey & 0x1FFFu);
      const float dd = __half2float(__ushort_as_half((unsigned short)(myKey >> 16)));
      if (y[col] == y[rowbase + row]) { contrib = -dd - logden; cmf = 1.0f; }
    }
    contrib += __shfl_xor(contrib, 1);  contrib += __shfl_xor(contrib, 2);
    contrib += __shfl_xor(contrib, 4);  contrib += __shfl_xor(contrib, 8);
    contrib += __shfl_xor(contrib, 16); contrib += __shfl_xor(contrib, 32);
    cmf += __shfl_xor(cmf, 1);  cmf += __shfl_xor(cmf, 2);
    cmf += __shfl_xor(cmf, 4);  cmf += __shfl_xor(cmf, 8);
    cmf += __shfl_xor(cmf, 16); cmf += __shfl_xor(cmf, 32);
    if (cmf > 0.0f) wsum += contrib / cmf;
  }
  if (l == 0) atomicAdd(out, wsum * (-1.0f / 8192.0f));
}

// ---------------------------------------------------------------------------
extern "C" void kernel_launch(void* const* d_in, const int* in_sizes, int n_in,
                              void* d_out, int out_size, void* d_ws, size_t ws_size,
                              hipStream_t stream) {
  const float* x = (const float*)d_in[0];
  const int* y = (const int*)d_in[1];
  float* out = (float*)d_out;
  char* ws = (char*)d_ws;

  float*          nrm = (float*)(ws + OFF_NRM);
  unsigned short* xb  = (unsigned short*)(ws + OFF_XB);

  k_prep<<<2048, 256,  0, stream>>>(x, xb, nrm, out);
  k_mega<<<256,  1024, 0, stream>>>(xb, nrm, y, out);
}

// Round 15
// 171.147 us; speedup vs baseline: 1.0958x; 1.0958x over previous
//
#include <hip/hip_runtime.h>
#include <hip/hip_fp16.h>

// ---------------------------------------------------------------------------
// ClassificationKNNLoss on MI355X — R15: mega-kernel, 16-row blocks.
//   k_prep : norms + bf16 convert with granule-XOR swizzle (+ zeroes d_out)
//   k_mega : 512 blocks x 512 thr; each block owns 16 rows x ALL 8192 cols.
//            B read DIRECT from global (L2-hot; no write stream). Zero
//            main-loop barriers/LDS. Per-thread sorted top-2 keys + denom in
//            regs; top-16 + label + loss merged in-block.
// R13: structure right but 1 block/CU (8 waves) -> latency-bound (occ 19%).
// R14: 1024-thr block + launch_bounds(1024,4) capped VGPR at 64 -> spills
//      (FETCH 198MB, WRITE 93MB). R15: halve rows/block instead — per-thread
//      state ~90 VGPR fits the 128 cap, 2 blocks/CU = 16 waves/CU.
// ---------------------------------------------------------------------------

typedef __attribute__((ext_vector_type(8))) short s8v;       // 8 x bf16 (4 VGPR)
typedef __attribute__((ext_vector_type(4))) float f32x4;     // MFMA acc

#define NK 256

template <bool B> struct BoolC { static constexpr bool value = B; };

// ws byte offsets
#define OFF_NRM 0                // f32[8192]
#define OFF_XB  32768            // u16[8192*256] swizzled bf16 (4.19MB)

__device__ __forceinline__ unsigned short f2bf(float f) {
  unsigned u = __float_as_uint(f);
  return (unsigned short)((u + 0x7FFFu + ((u >> 16) & 1u)) >> 16);  // RNE
}

__device__ __forceinline__ unsigned umin32(unsigned a, unsigned b) { return a < b ? a : b; }
__device__ __forceinline__ unsigned umax32(unsigned a, unsigned b) { return a > b ? a : b; }

// ---------------------------------------------------------------- k_prep ----
// xb[(r,k)] stored at u16 index r*256 + ((k>>3) ^ (r&7))*8 + (k&7)
__global__ __launch_bounds__(256) void k_prep(const float* __restrict__ x,
                                              unsigned short* __restrict__ xb,
                                              float* __restrict__ nrm,
                                              float* __restrict__ out) {
  if (blockIdx.x == 0 && threadIdx.x == 0) out[0] = 0.0f;
  const int w = threadIdx.x >> 6, l = threadIdx.x & 63;
  const int r = blockIdx.x * 4 + w;
  const float4 xv = *reinterpret_cast<const float4*>(x + r * NK + l * 4);
  float ns = xv.x * xv.x + xv.y * xv.y + xv.z * xv.z + xv.w * xv.w;
  ns += __shfl_xor(ns, 1);  ns += __shfl_xor(ns, 2);  ns += __shfl_xor(ns, 4);
  ns += __shfl_xor(ns, 8);  ns += __shfl_xor(ns, 16); ns += __shfl_xor(ns, 32);
  if (l == 0) nrm[r] = ns;
  ushort4 bv;
  bv.x = f2bf(xv.x); bv.y = f2bf(xv.y); bv.z = f2bf(xv.z); bv.w = f2bf(xv.w);
  const int gs = (l >> 1) ^ (r & 7);
  *reinterpret_cast<ushort4*>(xb + r * NK + gs * 8 + (l & 1) * 4) = bv;
}

// ---------------------------------------------------------------- k_mega ----
// 512 blocks (2/CU) x 512 thr (8 waves). Block = rows [rb*16, rb*16+16).
// Wave w sweeps 64-col tiles t = w + 8i (i=0..15).
__global__ __launch_bounds__(512, 4) void k_mega(const unsigned short* __restrict__ xb,
                                                 const float* __restrict__ nrm,
                                                 const int* __restrict__ y,
                                                 float* __restrict__ out) {
  __shared__ float ncsAll[8192];      // all column norms (32KB)
  __shared__ float dpart[16];         // per-row denom
  __shared__ unsigned cl[16][256];    // per-row candidate lists (16KB)
  const int tid = threadIdx.x;
  const int w = tid >> 6, l = tid & 63, l15 = l & 15, l4 = l >> 4;
  const int rb = blockIdx.x;
  const int rowbase = rb * 16;

  #pragma unroll
  for (int j = 0; j < 16; ++j) ncsAll[tid + j * 512] = nrm[tid + j * 512];
  if (tid < 16) dpart[tid] = 0.0f;

  s8v A[8];  // this block's 16 rows x K=256, register-resident (32 VGPR)
  {
    const int rr = rowbase + l15;
    #pragma unroll
    for (int kf = 0; kf < 8; ++kf) {
      const int g = ((kf << 2) | l4) ^ (rr & 7);
      A[kf] = *reinterpret_cast<const s8v*>(xb + rr * NK + g * 8);
    }
  }
  float nr[4], dn[4];
  unsigned s0[4], s1[4];  // per-thread sorted top-2 keys per row
  #pragma unroll
  for (int q = 0; q < 4; ++q) {
    nr[q] = nrm[rowbase + l4 * 4 + q];
    dn[q] = 0.0f;
    s0[q] = 0xFFFFFFFFu;
    s1[q] = 0xFFFFFFFFu;
  }

  int koff[8];  // per-lane granule byte offset within a column's 512B row
  #pragma unroll
  for (int kf = 0; kf < 8; ++kf)
    koff[kf] = ((((kf << 2) | l4) ^ (l15 & 7)) << 4);
  const char* xbc = (const char*)xb;
  const int tdg = rb >> 2;            // tile containing this block's diagonal

  __syncthreads();                    // ncsAll/dpart published

  for (int i = 0; i < 16; ++i) {
    const int t = w + i * 8;
    const int cbase = t * 64;
    const char* bp = xbc + (size_t)(cbase + l15) * 512;
    f32x4 acc[4];
    #pragma unroll
    for (int cf = 0; cf < 4; ++cf) {
      f32x4 z = {0.f, 0.f, 0.f, 0.f};
      acc[cf] = z;
    }
    #pragma unroll
    for (int kf = 0; kf < 8; ++kf) {
      const s8v b0 = *reinterpret_cast<const s8v*>(bp + koff[kf]);
      const s8v b1 = *reinterpret_cast<const s8v*>(bp + 8192 + koff[kf]);
      const s8v b2 = *reinterpret_cast<const s8v*>(bp + 16384 + koff[kf]);
      const s8v b3 = *reinterpret_cast<const s8v*>(bp + 24576 + koff[kf]);
      acc[0] = __builtin_amdgcn_mfma_f32_16x16x32_bf16(A[kf], b0, acc[0], 0, 0, 0);
      acc[1] = __builtin_amdgcn_mfma_f32_16x16x32_bf16(A[kf], b1, acc[1], 0, 0, 0);
      acc[2] = __builtin_amdgcn_mfma_f32_16x16x32_bf16(A[kf], b2, acc[2], 0, 0, 0);
      acc[3] = __builtin_amdgcn_mfma_f32_16x16x32_bf16(A[kf], b3, acc[3], 0, 0, 0);
    }
    float nc[4];
    #pragma unroll
    for (int cf = 0; cf < 4; ++cf) nc[cf] = ncsAll[cbase + cf * 16 + l15];
    auto epi = [&](auto dgc) {
      constexpr bool DG = decltype(dgc)::value;
      #pragma unroll
      for (int cf = 0; cf < 4; ++cf) {
        const unsigned colg = (unsigned)(cbase + cf * 16 + l15);
        #pragma unroll
        for (int q = 0; q < 4; ++q) {
          const unsigned rowg = (unsigned)(rowbase + l4 * 4 + q);
          float sq = fmaf(acc[cf][q], -2.0f, nr[q] + nc[cf]);
          if (DG) sq = fmaxf(sq, 0.0f);
          const float d = __builtin_amdgcn_sqrtf(sq);
          float e = __expf(-d);
          unsigned k = ((unsigned)__half_as_ushort(__float2half(d)) << 16) | colg;
          if (DG) {
            const bool nd = (rowg != colg);
            e = nd ? e : 0.0f;
            k = nd ? k : 0xFFFFFFFFu;
          }
          dn[q] += e;
          const unsigned ev = umax32(s0[q], k);
          s0[q] = umin32(s0[q], k);
          s1[q] = umin32(s1[q], ev);
        }
      }
    };
    if (t == tdg) epi(BoolC<true>{});
    else          epi(BoolC<false>{});
  }

  // ---- in-block merge (replaces k_fin) ----
  #pragma unroll
  for (int q = 0; q < 4; ++q) {
    float vs = dn[q];
    vs += __shfl_xor(vs, 1); vs += __shfl_xor(vs, 2);
    vs += __shfl_xor(vs, 4); vs += __shfl_xor(vs, 8);
    const int row16 = l4 * 4 + q;
    if (l15 == 0) atomicAdd(&dpart[row16], vs);
    cl[row16][w * 32 + l15 * 2]     = s0[q];
    cl[row16][w * 32 + l15 * 2 + 1] = s1[q];
  }
  __syncthreads();

  float wsum = 0.0f;
  for (int rr = 0; rr < 2; ++rr) {   // wave w finalizes rows 2w, 2w+1
    const int row = w * 2 + rr;
    unsigned kk[4];
    #pragma unroll
    for (int j = 0; j < 4; ++j) kk[j] = cl[row][l * 4 + j];
    unsigned myKey = 0xFFFFFFFFu;
    for (int pp = 0; pp < 16; ++pp) {
      const unsigned lm = umin32(umin32(kk[0], kk[1]), umin32(kk[2], kk[3]));
      unsigned m = lm;
      m = umin32(m, __shfl_xor(m, 1));  m = umin32(m, __shfl_xor(m, 2));
      m = umin32(m, __shfl_xor(m, 4));  m = umin32(m, __shfl_xor(m, 8));
      m = umin32(m, __shfl_xor(m, 16)); m = umin32(m, __shfl_xor(m, 32));
      const unsigned long long bal = __ballot(lm == m);
      const int owner = (int)__ffsll(bal) - 1;
      if (l == owner) {
        bool f = false;
        #pragma unroll
        for (int j = 0; j < 4; ++j)
          if (!f && kk[j] == m) { kk[j] = 0xFFFFFFFFu; f = true; }
      }
      if (l == pp) myKey = m;
    }
    const float logden = __logf(dpart[row]);
    float contrib = 0.0f, cmf = 0.0f;
    if (l < 16 && myKey != 0xFFFFFFFFu) {
      const int col = (int)(myKey & 0x1FFFu);
      const float dd = __half2float(__ushort_as_half((unsigned short)(myKey >> 16)));
      if (y[col] == y[rowbase + row]) { contrib = -dd - logden; cmf = 1.0f; }
    }
    contrib += __shfl_xor(contrib, 1);  contrib += __shfl_xor(contrib, 2);
    contrib += __shfl_xor(contrib, 4);  contrib += __shfl_xor(contrib, 8);
    contrib += __shfl_xor(contrib, 16); contrib += __shfl_xor(contrib, 32);
    cmf += __shfl_xor(cmf, 1);  cmf += __shfl_xor(cmf, 2);
    cmf += __shfl_xor(cmf, 4);  cmf += __shfl_xor(cmf, 8);
    cmf += __shfl_xor(cmf, 16); cmf += __shfl_xor(cmf, 32);
    if (cmf > 0.0f) wsum += contrib / cmf;
  }
  if (l == 0) atomicAdd(out, wsum * (-1.0f / 8192.0f));
}

// ---------------------------------------------------------------------------
extern "C" void kernel_launch(void* const* d_in, const int* in_sizes, int n_in,
                              void* d_out, int out_size, void* d_ws, size_t ws_size,
                              hipStream_t stream) {
  const float* x = (const float*)d_in[0];
  const int* y = (const int*)d_in[1];
  float* out = (float*)d_out;
  char* ws = (char*)d_ws;

  float*          nrm = (float*)(ws + OFF_NRM);
  unsigned short* xb  = (unsigned short*)(ws + OFF_XB);

  k_prep<<<2048, 256, 0, stream>>>(x, xb, nrm, out);
  k_mega<<<512,  512, 0, stream>>>(xb, nrm, y, out);
}